// Round 3
// baseline (168.934 us; speedup 1.0000x reference)
//
#include <hip/hip_runtime.h>
#include <math.h>

// BispectrumCalculator:
//   y = fft(target)  [B,T,N] complex
//   Bx[k,l] = y[k] * conj(y[l]) * y[(l-k) mod N]
//   source = stack([Bx.re, Bx.im], ch).mean(T)  -> [B, 2, N, N]
//   outputs: (source, target)  -> d_out = source flat (16,777,216) ++ target flat (65,536)
//
// Window model (r2-r8): harness re-poison of d_ws (257 MiB, ~46us) + d_out
// (64 MiB, ~11us) is inside the measured window; controllable slice (dft +
// bispec) ~30us of the 87us window.
//
// r8: bispec widened to K=8 rows x C=4 adjacent cols per thread (32
// outputs), 1024 blocks: (a) 4 blocks/CU all co-resident at 32 KiB LDS
// (r7's 2048 blocks ran as 5-resident + 3-tail rounds), (b) 23 LDS reads
// per 32 outputs per t (11-wide shared window + 8 av broadcast + 4 bb),
// (c) staging traffic halved. __launch_bounds__(256,4) pins VGPR <= 128
// so 4 blocks/CU fit. dft unchanged from r7 (Hermitian half-spectrum).

#define NN 512
#define TT 4
#define BB 32

// bijective within each 64-entry (512 B) float2 tile
__device__ __forceinline__ int sw_idx(int idx) {
    return (idx & ~63) | ((idx & 3) << 4) | ((idx >> 2) & 15);
}

// ---------------------------------------------------------------------------
// Kernel A: Hermitian DFT-512 per (b,t)  (unchanged from r7).
// Grid = 128 bt x 4 kq = 512 blocks, 256 threads = 64 kl x 4 nh.
// k = kq*64 + kl in [0,256); each thread sums n in [nh*128, nh*128+128).
// Rotor seeds via exact mod-512 phase reduction; nh partials combined in
// LDS; nh==0 stores y[k] and conj to y[512-k]. kq==0 also computes y[256]
// (alternating sum, +1 FMA/n) and copies the target row to the output tail.
// ---------------------------------------------------------------------------
__global__ __launch_bounds__(256) void dft_kernel(const float* __restrict__ x,
                                                  float2* __restrict__ y,
                                                  float* __restrict__ tail) {
    __shared__ float2 part[192];      // nh = 1..3 partials, [nh-1][kl]
    __shared__ float  salt[4];        // alternating-sum partials per nh

    int bt = blockIdx.x >> 2;
    int kq = blockIdx.x & 3;
    int kl = threadIdx.x & 63;
    int nh = threadIdx.x >> 6;
    int k  = (kq << 6) | kl;          // [0,256)
    const float* xp = x + (size_t)bt * NN;

    if (kq == 0 && nh == 0) {
        // target passthrough: 64 lanes x 2 float4 = 2 KiB row
        ((float4*)(tail + (size_t)bt * NN))[kl]      = ((const float4*)xp)[kl];
        ((float4*)(tail + (size_t)bt * NN))[kl + 64] = ((const float4*)xp)[kl + 64];
    }

    int n0 = nh << 7;  // 0,128,256,384
    const float twopi_n = -2.0f * (float)M_PI / (float)NN;

    float2 w0, w1, w2, w3;
    float s4, c4;
    {
        int m0 = (k * (n0 + 0)) & (NN - 1);
        int m1 = (k * (n0 + 1)) & (NN - 1);
        int m2 = (k * (n0 + 2)) & (NN - 1);
        int m3 = (k * (n0 + 3)) & (NN - 1);
        int m4 = (k * 4) & (NN - 1);
        sincosf(twopi_n * (float)m0, &w0.y, &w0.x);
        sincosf(twopi_n * (float)m1, &w1.y, &w1.x);
        sincosf(twopi_n * (float)m2, &w2.y, &w2.x);
        sincosf(twopi_n * (float)m3, &w3.y, &w3.x);
        sincosf(twopi_n * (float)m4, &s4, &c4);
    }

    float2 a0 = make_float2(0.f, 0.f), a1 = a0, a2 = a0, a3 = a0;
    float sa = 0.f;  // alternating sum partial (kq==0 only)

    if (kq == 0) {
        #pragma unroll 4
        for (int n = n0; n < n0 + 128; n += 4) {
            float x0 = xp[n];
            float x1 = xp[n + 1];
            float x2 = xp[n + 2];
            float x3 = xp[n + 3];
            sa += (x0 - x1) + (x2 - x3);   // n0 even -> signs +,-,+,-
            a0.x += x0 * w0.x; a0.y += x0 * w0.y;
            a1.x += x1 * w1.x; a1.y += x1 * w1.y;
            a2.x += x2 * w2.x; a2.y += x2 * w2.y;
            a3.x += x3 * w3.x; a3.y += x3 * w3.y;
            float t;
            t = w0.x * c4 - w0.y * s4; w0.y = w0.x * s4 + w0.y * c4; w0.x = t;
            t = w1.x * c4 - w1.y * s4; w1.y = w1.x * s4 + w1.y * c4; w1.x = t;
            t = w2.x * c4 - w2.y * s4; w2.y = w2.x * s4 + w2.y * c4; w2.x = t;
            t = w3.x * c4 - w3.y * s4; w3.y = w3.x * s4 + w3.y * c4; w3.x = t;
        }
    } else {
        #pragma unroll 4
        for (int n = n0; n < n0 + 128; n += 4) {
            float x0 = xp[n];
            float x1 = xp[n + 1];
            float x2 = xp[n + 2];
            float x3 = xp[n + 3];
            a0.x += x0 * w0.x; a0.y += x0 * w0.y;
            a1.x += x1 * w1.x; a1.y += x1 * w1.y;
            a2.x += x2 * w2.x; a2.y += x2 * w2.y;
            a3.x += x3 * w3.x; a3.y += x3 * w3.y;
            float t;
            t = w0.x * c4 - w0.y * s4; w0.y = w0.x * s4 + w0.y * c4; w0.x = t;
            t = w1.x * c4 - w1.y * s4; w1.y = w1.x * s4 + w1.y * c4; w1.x = t;
            t = w2.x * c4 - w2.y * s4; w2.y = w2.x * s4 + w2.y * c4; w2.x = t;
            t = w3.x * c4 - w3.y * s4; w3.y = w3.x * s4 + w3.y * c4; w3.x = t;
        }
    }

    float re = (a0.x + a1.x) + (a2.x + a3.x);
    float im = (a0.y + a1.y) + (a2.y + a3.y);

    if (nh) {
        part[((nh - 1) << 6) + kl] = make_float2(re, im);
    }
    if (kq == 0 && kl == 0) {
        salt[nh] = sa;
    }
    __syncthreads();

    if (nh == 0) {
        float2 p0 = part[kl];
        float2 p1 = part[64 + kl];
        float2 p2 = part[128 + kl];
        float rr = ((re + p0.x) + (p1.x + p2.x));
        float ii = ((im + p0.y) + (p1.y + p2.y));
        float2* yb = y + (size_t)bt * NN;
        yb[k] = make_float2(rr, ii);
        if (k != 0) {
            yb[NN - k] = make_float2(rr, -ii);   // Hermitian mirror
        }
        if (kq == 0 && kl == 0) {
            yb[NN / 2] = make_float2((salt[0] + salt[1]) + (salt[2] + salt[3]), 0.f);
        }
    }
}

// ---------------------------------------------------------------------------
// Kernel B: bispectrum. Grid = B * 32 = 1024 blocks x 256 threads.
// Block = one b, 16 consecutive k-rows (2 kgroups x 8 rows), all 512 cols.
// Thread = 8 rows x 4 ADJACENT cols; shared 11-wide c-window per t.
// Swizzled doubled LDS ring keeps every read at the wave64 bank floor:
//     sw(idx) = (idx&~63) | ((idx&3)<<4) | ((idx>>2)&15)
// 92 ds_read_b64 / 32 outputs / thread; 16 dwordx4 stores.
// 4 blocks/CU, all co-resident (no second residency round).
// ---------------------------------------------------------------------------
__global__ __launch_bounds__(256, 4) void bispec_kernel(const float2* __restrict__ y,
                                                        float* __restrict__ out) {
    __shared__ float2 ring[TT * 2 * NN];  // 32 KiB, doubled + swizzled

    int b   = blockIdx.x >> 5;
    int kb  = blockIdx.x & 31;   // 16-row group
    int tid = threadIdx.x;

    // stage y[b] -> swizzled doubled ring (global: [t][256] float4)
    const float4* src = (const float4*)(y + (size_t)b * TT * NN);
    #pragma unroll
    for (int i = 0; i < 4; ++i) {
        int g = tid + 256 * i;          // [0,1024)
        int t = g >> 8;
        int j = g & 255;                // float4 index within t-row
        float4 v = src[g];
        int s0 = sw_idx((t << 10) + 2 * j);   // i0 even -> sw(i0+1)=sw(i0)+16
        ring[s0]       = make_float2(v.x, v.y);
        ring[s0 + 16]  = make_float2(v.z, v.w);
        ring[s0 + 512] = make_float2(v.x, v.y);   // doubled copy: sw(idx+512)=sw(idx)+512
        ring[s0 + 528] = make_float2(v.z, v.w);
    }
    __syncthreads();

    int kg    = tid >> 7;            // wave-uniform (waves 0,1 -> 0; 2,3 -> 1)
    int ll    = tid & 127;
    int l0    = ll << 2;             // 4 adjacent columns l0..l0+3
    int kbase = (kb << 4) | (kg << 3);  // this thread's 8 rows (kbase%8==0)

    // swizzled t=0 indices, reused across t via +t*1024 (commutes with sw)
    int w0 = (l0 - kbase - 7) & (NN - 1);  // window start; w0+10 < 1024 in doubled ring
    int swj[11];
    #pragma unroll
    for (int j = 0; j < 11; ++j) swj[j] = sw_idx(w0 + j);
    // kbase%8==0 -> av[kk] at sa0 + ((kk&3)<<4) + (kk>>2), all within one 64-tile
    int sa0 = sw_idx(kbase);
    int sb0 = sw_idx(l0);     // l0%4==0 -> bb[c] at sb0 + (c<<4)

    float r[8][4], q[8][4];
    #pragma unroll
    for (int kk = 0; kk < 8; ++kk)
        #pragma unroll
        for (int c = 0; c < 4; ++c) { r[kk][c] = 0.f; q[kk][c] = 0.f; }

    #pragma unroll
    for (int t = 0; t < TT; ++t) {
        const float2* rt = ring + (t << 10);
        float2 cw[11], bb[4];
        #pragma unroll
        for (int j = 0; j < 11; ++j) cw[j] = rt[swj[j]];       // lane-spread, conflict-free
        #pragma unroll
        for (int c = 0; c < 4; ++c)  bb[c] = rt[sb0 + (c << 4)];  // lane-spread

        #pragma unroll
        for (int kk = 0; kk < 8; ++kk) {
            float2 a = rt[sa0 + ((kk & 3) << 4) + (kk >> 2)];  // wave-uniform broadcast
            #pragma unroll
            for (int c = 0; c < 4; ++c) {
                float2 cv = cw[7 - kk + c];   // = y_t[(l0+c - kbase-kk) mod 512]
                float2 bv = bb[c];            // = y_t[l0+c]
                float ur = a.x * cv.x - a.y * cv.y;
                float ui = a.x * cv.y + a.y * cv.x;
                r[kk][c] += ur * bv.x + ui * bv.y;   // Re(a*cv*conj(bv))
                q[kk][c] += ui * bv.x - ur * bv.y;   // Im(a*cv*conj(bv))
            }
        }
    }

    float* outb = out + (size_t)b * 2 * NN * NN;
    #pragma unroll
    for (int kk = 0; kk < 8; ++kk) {
        size_t rk = (size_t)(kbase + kk) * NN + l0;
        float4 vr = make_float4(r[kk][0] * 0.25f, r[kk][1] * 0.25f,
                                r[kk][2] * 0.25f, r[kk][3] * 0.25f);
        float4 vq = make_float4(q[kk][0] * 0.25f, q[kk][1] * 0.25f,
                                q[kk][2] * 0.25f, q[kk][3] * 0.25f);
        *(float4*)(outb + rk)                    = vr;  // real ch
        *(float4*)(outb + (size_t)NN * NN + rk)  = vq;  // imag ch
    }
}

extern "C" void kernel_launch(void* const* d_in, const int* in_sizes, int n_in,
                              void* d_out, int out_size, void* d_ws, size_t ws_size,
                              hipStream_t stream) {
    const float* target = (const float*)d_in[0];
    float* out = (float*)d_out;
    // workspace: y spectrum, B*T*N complex64 = 512 KiB
    float2* y = (float2*)d_ws;
    float* tail = out + (size_t)BB * 2 * NN * NN;  // target passthrough

    dft_kernel<<<BB * TT * 4, 256, 0, stream>>>(target, y, tail);
    bispec_kernel<<<BB * 32, 256, 0, stream>>>(y, out);
}

// Round 5
// 90.876 us; speedup vs baseline: 1.8590x; 1.8590x over previous
//
#include <hip/hip_runtime.h>
#include <math.h>

// BispectrumCalculator:
//   y = fft(target)  [B,T,N] complex
//   Bx[k,l] = y[k] * conj(y[l]) * y[(l-k) mod N]
//   source = stack([Bx.re, Bx.im], ch).mean(T)  -> [B, 2, N, N]
//   outputs: (source, target)  -> d_out = source flat (16,777,216) ++ target flat (65,536)
//
// Window model (r2-r9): harness re-poison of d_ws (257 MiB, ~46us) + d_out
// (64 MiB, ~11us) is inside the measured window; controllable slice (dft +
// bispec) ~30us of the 87us window.
//
// r8 POST-MORTEM: __launch_bounds__(256,4) clamped the allocator to 64
// VGPR (8-waves/EU bucket); the K=8xC=4 tile needs ~110 live regs ->
// accumulators spilled to scratch (FETCH 113MB / WRITE 289MB, bispec
// 104us). r9/r10 = identical structure with plain __launch_bounds__(256):
// ~110-125 live regs fit the <=128 bucket -> 16 waves/CU = 4 blocks/CU
// co-resident (LDS caps at 5), zero spill. DO NOT re-add a min-waves hint
// to bispec_kernel: the allocator rounds to the next occupancy bucket and
// the 64-VGPR bucket is a catastrophic spill regime for this tile.
// (r10 = r9 resubmitted verbatim; r9's bench failed on container acquire,
// not on the kernel.)

#define NN 512
#define TT 4
#define BB 32

// bijective within each 64-entry (512 B) float2 tile
__device__ __forceinline__ int sw_idx(int idx) {
    return (idx & ~63) | ((idx & 3) << 4) | ((idx >> 2) & 15);
}

// ---------------------------------------------------------------------------
// Kernel A: Hermitian DFT-512 per (b,t)  (unchanged from r7).
// Grid = 128 bt x 4 kq = 512 blocks, 256 threads = 64 kl x 4 nh.
// k = kq*64 + kl in [0,256); each thread sums n in [nh*128, nh*128+128).
// Rotor seeds via exact mod-512 phase reduction; nh partials combined in
// LDS; nh==0 stores y[k] and conj to y[512-k]. kq==0 also computes y[256]
// (alternating sum, +1 FMA/n) and copies the target row to the output tail.
// ---------------------------------------------------------------------------
__global__ __launch_bounds__(256) void dft_kernel(const float* __restrict__ x,
                                                  float2* __restrict__ y,
                                                  float* __restrict__ tail) {
    __shared__ float2 part[192];      // nh = 1..3 partials, [nh-1][kl]
    __shared__ float  salt[4];        // alternating-sum partials per nh

    int bt = blockIdx.x >> 2;
    int kq = blockIdx.x & 3;
    int kl = threadIdx.x & 63;
    int nh = threadIdx.x >> 6;
    int k  = (kq << 6) | kl;          // [0,256)
    const float* xp = x + (size_t)bt * NN;

    if (kq == 0 && nh == 0) {
        // target passthrough: 64 lanes x 2 float4 = 2 KiB row
        ((float4*)(tail + (size_t)bt * NN))[kl]      = ((const float4*)xp)[kl];
        ((float4*)(tail + (size_t)bt * NN))[kl + 64] = ((const float4*)xp)[kl + 64];
    }

    int n0 = nh << 7;  // 0,128,256,384
    const float twopi_n = -2.0f * (float)M_PI / (float)NN;

    float2 w0, w1, w2, w3;
    float s4, c4;
    {
        int m0 = (k * (n0 + 0)) & (NN - 1);
        int m1 = (k * (n0 + 1)) & (NN - 1);
        int m2 = (k * (n0 + 2)) & (NN - 1);
        int m3 = (k * (n0 + 3)) & (NN - 1);
        int m4 = (k * 4) & (NN - 1);
        sincosf(twopi_n * (float)m0, &w0.y, &w0.x);
        sincosf(twopi_n * (float)m1, &w1.y, &w1.x);
        sincosf(twopi_n * (float)m2, &w2.y, &w2.x);
        sincosf(twopi_n * (float)m3, &w3.y, &w3.x);
        sincosf(twopi_n * (float)m4, &s4, &c4);
    }

    float2 a0 = make_float2(0.f, 0.f), a1 = a0, a2 = a0, a3 = a0;
    float sa = 0.f;  // alternating sum partial (kq==0 only)

    if (kq == 0) {
        #pragma unroll 4
        for (int n = n0; n < n0 + 128; n += 4) {
            float x0 = xp[n];
            float x1 = xp[n + 1];
            float x2 = xp[n + 2];
            float x3 = xp[n + 3];
            sa += (x0 - x1) + (x2 - x3);   // n0 even -> signs +,-,+,-
            a0.x += x0 * w0.x; a0.y += x0 * w0.y;
            a1.x += x1 * w1.x; a1.y += x1 * w1.y;
            a2.x += x2 * w2.x; a2.y += x2 * w2.y;
            a3.x += x3 * w3.x; a3.y += x3 * w3.y;
            float t;
            t = w0.x * c4 - w0.y * s4; w0.y = w0.x * s4 + w0.y * c4; w0.x = t;
            t = w1.x * c4 - w1.y * s4; w1.y = w1.x * s4 + w1.y * c4; w1.x = t;
            t = w2.x * c4 - w2.y * s4; w2.y = w2.x * s4 + w2.y * c4; w2.x = t;
            t = w3.x * c4 - w3.y * s4; w3.y = w3.x * s4 + w3.y * c4; w3.x = t;
        }
    } else {
        #pragma unroll 4
        for (int n = n0; n < n0 + 128; n += 4) {
            float x0 = xp[n];
            float x1 = xp[n + 1];
            float x2 = xp[n + 2];
            float x3 = xp[n + 3];
            a0.x += x0 * w0.x; a0.y += x0 * w0.y;
            a1.x += x1 * w1.x; a1.y += x1 * w1.y;
            a2.x += x2 * w2.x; a2.y += x2 * w2.y;
            a3.x += x3 * w3.x; a3.y += x3 * w3.y;
            float t;
            t = w0.x * c4 - w0.y * s4; w0.y = w0.x * s4 + w0.y * c4; w0.x = t;
            t = w1.x * c4 - w1.y * s4; w1.y = w1.x * s4 + w1.y * c4; w1.x = t;
            t = w2.x * c4 - w2.y * s4; w2.y = w2.x * s4 + w2.y * c4; w2.x = t;
            t = w3.x * c4 - w3.y * s4; w3.y = w3.x * s4 + w3.y * c4; w3.x = t;
        }
    }

    float re = (a0.x + a1.x) + (a2.x + a3.x);
    float im = (a0.y + a1.y) + (a2.y + a3.y);

    if (nh) {
        part[((nh - 1) << 6) + kl] = make_float2(re, im);
    }
    if (kq == 0 && kl == 0) {
        salt[nh] = sa;
    }
    __syncthreads();

    if (nh == 0) {
        float2 p0 = part[kl];
        float2 p1 = part[64 + kl];
        float2 p2 = part[128 + kl];
        float rr = ((re + p0.x) + (p1.x + p2.x));
        float ii = ((im + p0.y) + (p1.y + p2.y));
        float2* yb = y + (size_t)bt * NN;
        yb[k] = make_float2(rr, ii);
        if (k != 0) {
            yb[NN - k] = make_float2(rr, -ii);   // Hermitian mirror
        }
        if (kq == 0 && kl == 0) {
            yb[NN / 2] = make_float2((salt[0] + salt[1]) + (salt[2] + salt[3]), 0.f);
        }
    }
}

// ---------------------------------------------------------------------------
// Kernel B: bispectrum. Grid = B * 32 = 1024 blocks x 256 threads.
// Block = one b, 16 consecutive k-rows (2 kgroups x 8 rows), all 512 cols.
// Thread = 8 rows x 4 ADJACENT cols; shared 11-wide c-window per t.
// Swizzled doubled LDS ring keeps every read at the wave64 bank floor:
//     sw(idx) = (idx&~63) | ((idx&3)<<4) | ((idx>>2)&15)
// 92 ds_read_b64 / 32 outputs / thread; 16 dwordx4 stores.
// Plain __launch_bounds__(256): ~110-125 live regs -> <=128 VGPR bucket
// -> 4 blocks/CU co-resident. (r8's min-waves hint forced 64 VGPR: spills.)
// ---------------------------------------------------------------------------
__global__ __launch_bounds__(256) void bispec_kernel(const float2* __restrict__ y,
                                                     float* __restrict__ out) {
    __shared__ float2 ring[TT * 2 * NN];  // 32 KiB, doubled + swizzled

    int b   = blockIdx.x >> 5;
    int kb  = blockIdx.x & 31;   // 16-row group
    int tid = threadIdx.x;

    // stage y[b] -> swizzled doubled ring (global: [t][256] float4)
    const float4* src = (const float4*)(y + (size_t)b * TT * NN);
    #pragma unroll
    for (int i = 0; i < 4; ++i) {
        int g = tid + 256 * i;          // [0,1024)
        int t = g >> 8;
        int j = g & 255;                // float4 index within t-row
        float4 v = src[g];
        int s0 = sw_idx((t << 10) + 2 * j);   // i0 even -> sw(i0+1)=sw(i0)+16
        ring[s0]       = make_float2(v.x, v.y);
        ring[s0 + 16]  = make_float2(v.z, v.w);
        ring[s0 + 512] = make_float2(v.x, v.y);   // doubled copy: sw(idx+512)=sw(idx)+512
        ring[s0 + 528] = make_float2(v.z, v.w);
    }
    __syncthreads();

    int kg    = tid >> 7;            // wave-uniform (waves 0,1 -> 0; 2,3 -> 1)
    int ll    = tid & 127;
    int l0    = ll << 2;             // 4 adjacent columns l0..l0+3
    int kbase = (kb << 4) | (kg << 3);  // this thread's 8 rows (kbase%8==0)

    // swizzled t=0 indices, reused across t via +t*1024 (commutes with sw)
    int w0 = (l0 - kbase - 7) & (NN - 1);  // window start; w0+10 < 1024 in doubled ring
    int swj[11];
    #pragma unroll
    for (int j = 0; j < 11; ++j) swj[j] = sw_idx(w0 + j);
    // kbase%8==0 -> av[kk] at sa0 + ((kk&3)<<4) + (kk>>2), all within one 64-tile
    int sa0 = sw_idx(kbase);
    int sb0 = sw_idx(l0);     // l0%4==0 -> bb[c] at sb0 + (c<<4)

    float r[8][4], q[8][4];
    #pragma unroll
    for (int kk = 0; kk < 8; ++kk)
        #pragma unroll
        for (int c = 0; c < 4; ++c) { r[kk][c] = 0.f; q[kk][c] = 0.f; }

    #pragma unroll
    for (int t = 0; t < TT; ++t) {
        const float2* rt = ring + (t << 10);
        float2 cw[11], bb[4];
        #pragma unroll
        for (int j = 0; j < 11; ++j) cw[j] = rt[swj[j]];       // lane-spread, conflict-free
        #pragma unroll
        for (int c = 0; c < 4; ++c)  bb[c] = rt[sb0 + (c << 4)];  // lane-spread

        #pragma unroll
        for (int kk = 0; kk < 8; ++kk) {
            float2 a = rt[sa0 + ((kk & 3) << 4) + (kk >> 2)];  // wave-uniform broadcast
            #pragma unroll
            for (int c = 0; c < 4; ++c) {
                float2 cv = cw[7 - kk + c];   // = y_t[(l0+c - kbase-kk) mod 512]
                float2 bv = bb[c];            // = y_t[l0+c]
                float ur = a.x * cv.x - a.y * cv.y;
                float ui = a.x * cv.y + a.y * cv.x;
                r[kk][c] += ur * bv.x + ui * bv.y;   // Re(a*cv*conj(bv))
                q[kk][c] += ui * bv.x - ur * bv.y;   // Im(a*cv*conj(bv))
            }
        }
    }

    float* outb = out + (size_t)b * 2 * NN * NN;
    #pragma unroll
    for (int kk = 0; kk < 8; ++kk) {
        size_t rk = (size_t)(kbase + kk) * NN + l0;
        float4 vr = make_float4(r[kk][0] * 0.25f, r[kk][1] * 0.25f,
                                r[kk][2] * 0.25f, r[kk][3] * 0.25f);
        float4 vq = make_float4(q[kk][0] * 0.25f, q[kk][1] * 0.25f,
                                q[kk][2] * 0.25f, q[kk][3] * 0.25f);
        *(float4*)(outb + rk)                    = vr;  // real ch
        *(float4*)(outb + (size_t)NN * NN + rk)  = vq;  // imag ch
    }
}

extern "C" void kernel_launch(void* const* d_in, const int* in_sizes, int n_in,
                              void* d_out, int out_size, void* d_ws, size_t ws_size,
                              hipStream_t stream) {
    const float* target = (const float*)d_in[0];
    float* out = (float*)d_out;
    // workspace: y spectrum, B*T*N complex64 = 512 KiB
    float2* y = (float2*)d_ws;
    float* tail = out + (size_t)BB * 2 * NN * NN;  // target passthrough

    dft_kernel<<<BB * TT * 4, 256, 0, stream>>>(target, y, tail);
    bispec_kernel<<<BB * 32, 256, 0, stream>>>(y, out);
}

// Round 6
// 85.962 us; speedup vs baseline: 1.9652x; 1.0572x over previous
//
#include <hip/hip_runtime.h>
#include <math.h>

// BispectrumCalculator:
//   y = fft(target)  [B,T,N] complex
//   Bx[k,l] = y[k] * conj(y[l]) * y[(l-k) mod N]
//   source = stack([Bx.re, Bx.im], ch).mean(T)  -> [B, 2, N, N]
//   outputs: (source, target)  -> d_out = source flat (16,777,216) ++ target flat (65,536)
//
// Window model (r2-r11): harness re-poison of d_ws (257 MiB, ~46us) +
// d_out (64 MiB, ~11us) is inside the measured window; controllable slice
// (dft + bispec) ~30us of the ~87us window.
//
// History: r7 (K=4xC=4, 2048 blocks, doubled ring) = 87.1us best.
// r8: launch_bounds(256,4) forced 64 VGPR -> spills -> 169us. NEVER add a
//     min-waves hint to bispec; the 64-VGPR bucket spills this tile.
// r9/r10: K=8xC=4 (1024 blocks) -> 90.9us: VGPR >128 -> 3 blocks/CU vs 4
//     needed -> 25% idle tail. Wider tiles lose to occupancy quantization.
// r11: revert to r7 tile + free fixes: (a) SINGLE 16 KiB ring -- the wrap
//     is folded into the precomputed swizzled indices (&511 at precompute,
//     zero inner-loop cost), LDS cap 5 -> 10 blocks/CU so bispec becomes
//     VGPR-limited at ~6/CU (6+2 rounds vs 5+3); (b) av loaded in-loop
//     (wave-uniform broadcast) to trim ~8 live regs.

#define NN 512
#define TT 4
#define BB 32

// bijective within each 64-entry (512 B) float2 tile
__device__ __forceinline__ int sw_idx(int idx) {
    return (idx & ~63) | ((idx & 3) << 4) | ((idx >> 2) & 15);
}

// ---------------------------------------------------------------------------
// Kernel A: Hermitian DFT-512 per (b,t)  (unchanged from r7).
// Grid = 128 bt x 4 kq = 512 blocks, 256 threads = 64 kl x 4 nh.
// k = kq*64 + kl in [0,256); each thread sums n in [nh*128, nh*128+128).
// Rotor seeds via exact mod-512 phase reduction; nh partials combined in
// LDS; nh==0 stores y[k] and conj to y[512-k]. kq==0 also computes y[256]
// (alternating sum, +1 FMA/n) and copies the target row to the output tail.
// ---------------------------------------------------------------------------
__global__ __launch_bounds__(256) void dft_kernel(const float* __restrict__ x,
                                                  float2* __restrict__ y,
                                                  float* __restrict__ tail) {
    __shared__ float2 part[192];      // nh = 1..3 partials, [nh-1][kl]
    __shared__ float  salt[4];        // alternating-sum partials per nh

    int bt = blockIdx.x >> 2;
    int kq = blockIdx.x & 3;
    int kl = threadIdx.x & 63;
    int nh = threadIdx.x >> 6;
    int k  = (kq << 6) | kl;          // [0,256)
    const float* xp = x + (size_t)bt * NN;

    if (kq == 0 && nh == 0) {
        // target passthrough: 64 lanes x 2 float4 = 2 KiB row
        ((float4*)(tail + (size_t)bt * NN))[kl]      = ((const float4*)xp)[kl];
        ((float4*)(tail + (size_t)bt * NN))[kl + 64] = ((const float4*)xp)[kl + 64];
    }

    int n0 = nh << 7;  // 0,128,256,384
    const float twopi_n = -2.0f * (float)M_PI / (float)NN;

    float2 w0, w1, w2, w3;
    float s4, c4;
    {
        int m0 = (k * (n0 + 0)) & (NN - 1);
        int m1 = (k * (n0 + 1)) & (NN - 1);
        int m2 = (k * (n0 + 2)) & (NN - 1);
        int m3 = (k * (n0 + 3)) & (NN - 1);
        int m4 = (k * 4) & (NN - 1);
        sincosf(twopi_n * (float)m0, &w0.y, &w0.x);
        sincosf(twopi_n * (float)m1, &w1.y, &w1.x);
        sincosf(twopi_n * (float)m2, &w2.y, &w2.x);
        sincosf(twopi_n * (float)m3, &w3.y, &w3.x);
        sincosf(twopi_n * (float)m4, &s4, &c4);
    }

    float2 a0 = make_float2(0.f, 0.f), a1 = a0, a2 = a0, a3 = a0;
    float sa = 0.f;  // alternating sum partial (kq==0 only)

    if (kq == 0) {
        #pragma unroll 4
        for (int n = n0; n < n0 + 128; n += 4) {
            float x0 = xp[n];
            float x1 = xp[n + 1];
            float x2 = xp[n + 2];
            float x3 = xp[n + 3];
            sa += (x0 - x1) + (x2 - x3);   // n0 even -> signs +,-,+,-
            a0.x += x0 * w0.x; a0.y += x0 * w0.y;
            a1.x += x1 * w1.x; a1.y += x1 * w1.y;
            a2.x += x2 * w2.x; a2.y += x2 * w2.y;
            a3.x += x3 * w3.x; a3.y += x3 * w3.y;
            float t;
            t = w0.x * c4 - w0.y * s4; w0.y = w0.x * s4 + w0.y * c4; w0.x = t;
            t = w1.x * c4 - w1.y * s4; w1.y = w1.x * s4 + w1.y * c4; w1.x = t;
            t = w2.x * c4 - w2.y * s4; w2.y = w2.x * s4 + w2.y * c4; w2.x = t;
            t = w3.x * c4 - w3.y * s4; w3.y = w3.x * s4 + w3.y * c4; w3.x = t;
        }
    } else {
        #pragma unroll 4
        for (int n = n0; n < n0 + 128; n += 4) {
            float x0 = xp[n];
            float x1 = xp[n + 1];
            float x2 = xp[n + 2];
            float x3 = xp[n + 3];
            a0.x += x0 * w0.x; a0.y += x0 * w0.y;
            a1.x += x1 * w1.x; a1.y += x1 * w1.y;
            a2.x += x2 * w2.x; a2.y += x2 * w2.y;
            a3.x += x3 * w3.x; a3.y += x3 * w3.y;
            float t;
            t = w0.x * c4 - w0.y * s4; w0.y = w0.x * s4 + w0.y * c4; w0.x = t;
            t = w1.x * c4 - w1.y * s4; w1.y = w1.x * s4 + w1.y * c4; w1.x = t;
            t = w2.x * c4 - w2.y * s4; w2.y = w2.x * s4 + w2.y * c4; w2.x = t;
            t = w3.x * c4 - w3.y * s4; w3.y = w3.x * s4 + w3.y * c4; w3.x = t;
        }
    }

    float re = (a0.x + a1.x) + (a2.x + a3.x);
    float im = (a0.y + a1.y) + (a2.y + a3.y);

    if (nh) {
        part[((nh - 1) << 6) + kl] = make_float2(re, im);
    }
    if (kq == 0 && kl == 0) {
        salt[nh] = sa;
    }
    __syncthreads();

    if (nh == 0) {
        float2 p0 = part[kl];
        float2 p1 = part[64 + kl];
        float2 p2 = part[128 + kl];
        float rr = ((re + p0.x) + (p1.x + p2.x));
        float ii = ((im + p0.y) + (p1.y + p2.y));
        float2* yb = y + (size_t)bt * NN;
        yb[k] = make_float2(rr, ii);
        if (k != 0) {
            yb[NN - k] = make_float2(rr, -ii);   // Hermitian mirror
        }
        if (kq == 0 && kl == 0) {
            yb[NN / 2] = make_float2((salt[0] + salt[1]) + (salt[2] + salt[3]), 0.f);
        }
    }
}

// ---------------------------------------------------------------------------
// Kernel B: bispectrum. Grid = B * 64 = 2048 blocks x 256 threads.
// Block = one b, 8 consecutive k-rows (2 kgroups x 4 rows), all 512 cols.
// Thread = 4 rows x 4 ADJACENT cols; shared 7-wide c-window per t.
// SINGLE swizzled 16 KiB ring; the mod-512 wrap is folded into the
// precomputed swizzled indices (zero inner-loop cost):
//     sw(idx) = (idx&~63) | ((idx&3)<<4) | ((idx>>2)&15)
// ~60 ds_read_b64/thread, 8 dwordx4 stores. ~85 live regs -> VGPR-limited
// ~6 blocks/CU (LDS cap now 10) -> 6+2 rounds instead of 5+3.
// ---------------------------------------------------------------------------
__global__ __launch_bounds__(256) void bispec_kernel(const float2* __restrict__ y,
                                                     float* __restrict__ out) {
    __shared__ float2 ring[TT * NN];  // 16 KiB, swizzled, single copy

    int b   = blockIdx.x >> 6;
    int kb  = blockIdx.x & 63;   // 8-row group
    int tid = threadIdx.x;

    // stage y[b] -> swizzled ring (global: [t][256] float4)
    const float4* src = (const float4*)(y + (size_t)b * TT * NN);
    #pragma unroll
    for (int i = 0; i < 4; ++i) {
        int g = tid + 256 * i;          // [0,1024)
        int t = g >> 8;
        int j = g & 255;                // float4 index within t-row (512 float2)
        float4 v = src[g];
        int s0 = sw_idx((t << 9) + 2 * j);   // 2j even -> sw(2j+1)=sw(2j)+16
        ring[s0]      = make_float2(v.x, v.y);
        ring[s0 + 16] = make_float2(v.z, v.w);
    }
    __syncthreads();

    int kg    = tid >> 7;            // wave-uniform (waves 0,1 -> 0; 2,3 -> 1)
    int ll    = tid & 127;
    int l0    = ll << 2;             // 4 adjacent columns l0..l0+3
    int kbase = (kb << 3) | (kg << 2);  // this thread's 4 rows (kbase%4==0)

    // swizzled t=0 indices (wrap folded in), reused across t via +t*512
    int w0 = (l0 - kbase - 3) & (NN - 1);  // window start
    int swj[7];
    #pragma unroll
    for (int j = 0; j < 7; ++j) swj[j] = sw_idx((w0 + j) & (NN - 1));
    int sa0 = sw_idx(kbase);  // kbase%4==0 -> av[kk] at sa0 + (kk<<4)
    int sb0 = sw_idx(l0);     // l0%4==0   -> bb[c]  at sb0 + (c<<4)

    float r[4][4], q[4][4];
    #pragma unroll
    for (int kk = 0; kk < 4; ++kk)
        #pragma unroll
        for (int c = 0; c < 4; ++c) { r[kk][c] = 0.f; q[kk][c] = 0.f; }

    #pragma unroll
    for (int t = 0; t < TT; ++t) {
        const float2* rt = ring + (t << 9);
        float2 cw[7], bb[4];
        #pragma unroll
        for (int j = 0; j < 7; ++j) cw[j] = rt[swj[j]];          // lane-spread, conflict-free
        #pragma unroll
        for (int c = 0; c < 4; ++c)  bb[c] = rt[sb0 + (c << 4)]; // lane-spread

        #pragma unroll
        for (int kk = 0; kk < 4; ++kk) {
            float2 a = rt[sa0 + (kk << 4)];   // wave-uniform broadcast, loaded in-loop
            #pragma unroll
            for (int c = 0; c < 4; ++c) {
                float2 cv = cw[3 - kk + c];   // = y_t[(l0+c - kbase-kk) mod 512]
                float2 bv = bb[c];            // = y_t[l0+c]
                float ur = a.x * cv.x - a.y * cv.y;
                float ui = a.x * cv.y + a.y * cv.x;
                r[kk][c] += ur * bv.x + ui * bv.y;   // Re(a*cv*conj(bv))
                q[kk][c] += ui * bv.x - ur * bv.y;   // Im(a*cv*conj(bv))
            }
        }
    }

    float* outb = out + (size_t)b * 2 * NN * NN;
    #pragma unroll
    for (int kk = 0; kk < 4; ++kk) {
        size_t rk = (size_t)(kbase + kk) * NN + l0;
        float4 vr = make_float4(r[kk][0] * 0.25f, r[kk][1] * 0.25f,
                                r[kk][2] * 0.25f, r[kk][3] * 0.25f);
        float4 vq = make_float4(q[kk][0] * 0.25f, q[kk][1] * 0.25f,
                                q[kk][2] * 0.25f, q[kk][3] * 0.25f);
        *(float4*)(outb + rk)                    = vr;  // real ch
        *(float4*)(outb + (size_t)NN * NN + rk)  = vq;  // imag ch
    }
}

extern "C" void kernel_launch(void* const* d_in, const int* in_sizes, int n_in,
                              void* d_out, int out_size, void* d_ws, size_t ws_size,
                              hipStream_t stream) {
    const float* target = (const float*)d_in[0];
    float* out = (float*)d_out;
    // workspace: y spectrum, B*T*N complex64 = 512 KiB
    float2* y = (float2*)d_ws;
    float* tail = out + (size_t)BB * 2 * NN * NN;  // target passthrough

    dft_kernel<<<BB * TT * 4, 256, 0, stream>>>(target, y, tail);
    bispec_kernel<<<BB * 64, 256, 0, stream>>>(y, out);
}

// Round 7
// 85.950 us; speedup vs baseline: 1.9655x; 1.0001x over previous
//
#include <hip/hip_runtime.h>
#include <math.h>

// BispectrumCalculator:
//   y = fft(target)  [B,T,N] complex
//   Bx[k,l] = y[k] * conj(y[l]) * y[(l-k) mod N]
//   source = stack([Bx.re, Bx.im], ch).mean(T)  -> [B, 2, N, N]
//   outputs: (source, target)  -> d_out = source flat (16,777,216) ++ target flat (65,536)
//
// Window model (r2-r12): harness re-poison of d_ws (257 MiB, ~46us) +
// d_out (64 MiB, ~11us) is inside the measured window; controllable slice
// (dft + bispec) ~29us of the 86us window.
//
// History: r7 = 87.1 (K=4xC=4, doubled ring). r8 = 169 (launch_bounds
// min-waves hint -> 64 VGPR -> spills; NEVER re-add). r9/r10 = 90.9
// (K=8xC=4: VGPR>128 -> 3/CU vs 4 needed -> idle tail). r11 = 86.0
// (single 16 KiB ring, wrap folded into precomputed swizzled indices).
//
// r12: bispec loop inversion for EARLY STORES. r11 was t-outer/kk-inner:
// all 32 outputs live to the end, one store burst after all compute ->
// kernel ~= compute (~8-10us) + serial HBM write drain (~11us). r12 is
// kk-outer/t-inner: bb[t][c] hoisted to regs (kk-invariant), per kk only
// its 4-wide window slice is re-read (swj[3-kk+c], +36 ds_reads/thread vs
// r11 -- still under the store roof), row stored immediately -> write
// drain overlaps compute. Accumulators 64->8 regs.

#define NN 512
#define TT 4
#define BB 32

// bijective within each 64-entry (512 B) float2 tile
__device__ __forceinline__ int sw_idx(int idx) {
    return (idx & ~63) | ((idx & 3) << 4) | ((idx >> 2) & 15);
}

// ---------------------------------------------------------------------------
// Kernel A: Hermitian DFT-512 per (b,t)  (unchanged from r7).
// Grid = 128 bt x 4 kq = 512 blocks, 256 threads = 64 kl x 4 nh.
// k = kq*64 + kl in [0,256); each thread sums n in [nh*128, nh*128+128).
// Rotor seeds via exact mod-512 phase reduction; nh partials combined in
// LDS; nh==0 stores y[k] and conj to y[512-k]. kq==0 also computes y[256]
// (alternating sum, +1 FMA/n) and copies the target row to the output tail.
// ---------------------------------------------------------------------------
__global__ __launch_bounds__(256) void dft_kernel(const float* __restrict__ x,
                                                  float2* __restrict__ y,
                                                  float* __restrict__ tail) {
    __shared__ float2 part[192];      // nh = 1..3 partials, [nh-1][kl]
    __shared__ float  salt[4];        // alternating-sum partials per nh

    int bt = blockIdx.x >> 2;
    int kq = blockIdx.x & 3;
    int kl = threadIdx.x & 63;
    int nh = threadIdx.x >> 6;
    int k  = (kq << 6) | kl;          // [0,256)
    const float* xp = x + (size_t)bt * NN;

    if (kq == 0 && nh == 0) {
        // target passthrough: 64 lanes x 2 float4 = 2 KiB row
        ((float4*)(tail + (size_t)bt * NN))[kl]      = ((const float4*)xp)[kl];
        ((float4*)(tail + (size_t)bt * NN))[kl + 64] = ((const float4*)xp)[kl + 64];
    }

    int n0 = nh << 7;  // 0,128,256,384
    const float twopi_n = -2.0f * (float)M_PI / (float)NN;

    float2 w0, w1, w2, w3;
    float s4, c4;
    {
        int m0 = (k * (n0 + 0)) & (NN - 1);
        int m1 = (k * (n0 + 1)) & (NN - 1);
        int m2 = (k * (n0 + 2)) & (NN - 1);
        int m3 = (k * (n0 + 3)) & (NN - 1);
        int m4 = (k * 4) & (NN - 1);
        sincosf(twopi_n * (float)m0, &w0.y, &w0.x);
        sincosf(twopi_n * (float)m1, &w1.y, &w1.x);
        sincosf(twopi_n * (float)m2, &w2.y, &w2.x);
        sincosf(twopi_n * (float)m3, &w3.y, &w3.x);
        sincosf(twopi_n * (float)m4, &s4, &c4);
    }

    float2 a0 = make_float2(0.f, 0.f), a1 = a0, a2 = a0, a3 = a0;
    float sa = 0.f;  // alternating sum partial (kq==0 only)

    if (kq == 0) {
        #pragma unroll 4
        for (int n = n0; n < n0 + 128; n += 4) {
            float x0 = xp[n];
            float x1 = xp[n + 1];
            float x2 = xp[n + 2];
            float x3 = xp[n + 3];
            sa += (x0 - x1) + (x2 - x3);   // n0 even -> signs +,-,+,-
            a0.x += x0 * w0.x; a0.y += x0 * w0.y;
            a1.x += x1 * w1.x; a1.y += x1 * w1.y;
            a2.x += x2 * w2.x; a2.y += x2 * w2.y;
            a3.x += x3 * w3.x; a3.y += x3 * w3.y;
            float t;
            t = w0.x * c4 - w0.y * s4; w0.y = w0.x * s4 + w0.y * c4; w0.x = t;
            t = w1.x * c4 - w1.y * s4; w1.y = w1.x * s4 + w1.y * c4; w1.x = t;
            t = w2.x * c4 - w2.y * s4; w2.y = w2.x * s4 + w2.y * c4; w2.x = t;
            t = w3.x * c4 - w3.y * s4; w3.y = w3.x * s4 + w3.y * c4; w3.x = t;
        }
    } else {
        #pragma unroll 4
        for (int n = n0; n < n0 + 128; n += 4) {
            float x0 = xp[n];
            float x1 = xp[n + 1];
            float x2 = xp[n + 2];
            float x3 = xp[n + 3];
            a0.x += x0 * w0.x; a0.y += x0 * w0.y;
            a1.x += x1 * w1.x; a1.y += x1 * w1.y;
            a2.x += x2 * w2.x; a2.y += x2 * w2.y;
            a3.x += x3 * w3.x; a3.y += x3 * w3.y;
            float t;
            t = w0.x * c4 - w0.y * s4; w0.y = w0.x * s4 + w0.y * c4; w0.x = t;
            t = w1.x * c4 - w1.y * s4; w1.y = w1.x * s4 + w1.y * c4; w1.x = t;
            t = w2.x * c4 - w2.y * s4; w2.y = w2.x * s4 + w2.y * c4; w2.x = t;
            t = w3.x * c4 - w3.y * s4; w3.y = w3.x * s4 + w3.y * c4; w3.x = t;
        }
    }

    float re = (a0.x + a1.x) + (a2.x + a3.x);
    float im = (a0.y + a1.y) + (a2.y + a3.y);

    if (nh) {
        part[((nh - 1) << 6) + kl] = make_float2(re, im);
    }
    if (kq == 0 && kl == 0) {
        salt[nh] = sa;
    }
    __syncthreads();

    if (nh == 0) {
        float2 p0 = part[kl];
        float2 p1 = part[64 + kl];
        float2 p2 = part[128 + kl];
        float rr = ((re + p0.x) + (p1.x + p2.x));
        float ii = ((im + p0.y) + (p1.y + p2.y));
        float2* yb = y + (size_t)bt * NN;
        yb[k] = make_float2(rr, ii);
        if (k != 0) {
            yb[NN - k] = make_float2(rr, -ii);   // Hermitian mirror
        }
        if (kq == 0 && kl == 0) {
            yb[NN / 2] = make_float2((salt[0] + salt[1]) + (salt[2] + salt[3]), 0.f);
        }
    }
}

// ---------------------------------------------------------------------------
// Kernel B: bispectrum. Grid = B * 64 = 2048 blocks x 256 threads.
// Block = one b, 8 consecutive k-rows (2 kgroups x 4 rows), all 512 cols.
// Thread = 4 rows x 4 ADJACENT cols. kk-OUTER / t-INNER with immediate
// per-row stores (write drain overlaps compute). bb[t][c] hoisted to regs;
// per kk only its 4-wide slice of the 7-window is read (swj[3-kk+c]); av
// is a wave-uniform broadcast. Single swizzled 16 KiB ring, wrap folded
// into precomputed indices:
//     sw(idx) = (idx&~63) | ((idx&3)<<4) | ((idx>>2)&15)
// 96 ds_read_b64/thread, 8 dwordx4 stores spread across the kernel.
// ---------------------------------------------------------------------------
__global__ __launch_bounds__(256) void bispec_kernel(const float2* __restrict__ y,
                                                     float* __restrict__ out) {
    __shared__ float2 ring[TT * NN];  // 16 KiB, swizzled, single copy

    int b   = blockIdx.x >> 6;
    int kb  = blockIdx.x & 63;   // 8-row group
    int tid = threadIdx.x;

    // stage y[b] -> swizzled ring (global: [t][256] float4)
    const float4* src = (const float4*)(y + (size_t)b * TT * NN);
    #pragma unroll
    for (int i = 0; i < 4; ++i) {
        int g = tid + 256 * i;          // [0,1024)
        int t = g >> 8;
        int j = g & 255;                // float4 index within t-row (512 float2)
        float4 v = src[g];
        int s0 = sw_idx((t << 9) + 2 * j);   // 2j even -> sw(2j+1)=sw(2j)+16
        ring[s0]      = make_float2(v.x, v.y);
        ring[s0 + 16] = make_float2(v.z, v.w);
    }
    __syncthreads();

    int kg    = tid >> 7;            // wave-uniform (waves 0,1 -> 0; 2,3 -> 1)
    int ll    = tid & 127;
    int l0    = ll << 2;             // 4 adjacent columns l0..l0+3
    int kbase = (kb << 3) | (kg << 2);  // this thread's 4 rows (kbase%4==0)

    // swizzled t=0 indices (wrap folded in), reused across t via +t*512
    int w0 = (l0 - kbase - 3) & (NN - 1);  // window start
    int swj[7];
    #pragma unroll
    for (int j = 0; j < 7; ++j) swj[j] = sw_idx((w0 + j) & (NN - 1));
    int sa0 = sw_idx(kbase);  // kbase%4==0 -> av[kk] at sa0 + (kk<<4)
    int sb0 = sw_idx(l0);     // l0%4==0   -> bb[c]  at sb0 + (c<<4)

    // hoist kk-invariant conj-source values: bb[t][c] (32 VGPR)
    float2 bbr[TT][4];
    #pragma unroll
    for (int t = 0; t < TT; ++t)
        #pragma unroll
        for (int c = 0; c < 4; ++c)
            bbr[t][c] = ring[(t << 9) + sb0 + (c << 4)];

    float* outb = out + (size_t)b * 2 * NN * NN;

    #pragma unroll
    for (int kk = 0; kk < 4; ++kk) {
        float r[4] = {0.f, 0.f, 0.f, 0.f};
        float q[4] = {0.f, 0.f, 0.f, 0.f};

        #pragma unroll
        for (int t = 0; t < TT; ++t) {
            const float2* rt = ring + (t << 9);
            float2 a  = rt[sa0 + (kk << 4)];   // wave-uniform broadcast
            float2 cw0 = rt[swj[3 - kk + 0]];  // lane-spread, conflict-free
            float2 cw1 = rt[swj[3 - kk + 1]];
            float2 cw2 = rt[swj[3 - kk + 2]];
            float2 cw3 = rt[swj[3 - kk + 3]];
            float2 cwv[4] = {cw0, cw1, cw2, cw3};
            #pragma unroll
            for (int c = 0; c < 4; ++c) {
                float2 cv = cwv[c];           // = y_t[(l0+c - kbase-kk) mod 512]
                float2 bv = bbr[t][c];        // = y_t[l0+c]
                float ur = a.x * cv.x - a.y * cv.y;
                float ui = a.x * cv.y + a.y * cv.x;
                r[c] += ur * bv.x + ui * bv.y;   // Re(a*cv*conj(bv))
                q[c] += ui * bv.x - ur * bv.y;   // Im(a*cv*conj(bv))
            }
        }

        // store this k-row immediately -> overlaps later kk's compute
        size_t rk = (size_t)(kbase + kk) * NN + l0;
        float4 vr = make_float4(r[0] * 0.25f, r[1] * 0.25f,
                                r[2] * 0.25f, r[3] * 0.25f);
        float4 vq = make_float4(q[0] * 0.25f, q[1] * 0.25f,
                                q[2] * 0.25f, q[3] * 0.25f);
        *(float4*)(outb + rk)                   = vr;  // real ch
        *(float4*)(outb + (size_t)NN * NN + rk) = vq;  // imag ch
    }
}

extern "C" void kernel_launch(void* const* d_in, const int* in_sizes, int n_in,
                              void* d_out, int out_size, void* d_ws, size_t ws_size,
                              hipStream_t stream) {
    const float* target = (const float*)d_in[0];
    float* out = (float*)d_out;
    // workspace: y spectrum, B*T*N complex64 = 512 KiB
    float2* y = (float2*)d_ws;
    float* tail = out + (size_t)BB * 2 * NN * NN;  // target passthrough

    dft_kernel<<<BB * TT * 4, 256, 0, stream>>>(target, y, tail);
    bispec_kernel<<<BB * 64, 256, 0, stream>>>(y, out);
}